// Round 3
// baseline (117.334 us; speedup 1.0000x reference)
//
#include <hip/hip_runtime.h>

#define TPB 256
#define PTS 4          // query points per thread (2 x float2)
#define CHUNK 512      // database points per block (G = 16)

typedef float f2 __attribute__((ext_vector_type(2)));

// ws layout: part[bz][group][mx] floats (2 MB for B=2, G=16, mx=8192),
//            then prep[2N + 2M] float4 (512 KB): pos section, then xhat section.

// Pair-compute: identical FMA/min ordering to the verified kernel (absmax=0.0).
#define PAIR_COMPUTE(q0, q1)                                            \
    do {                                                                \
        _Pragma("unroll")                                               \
        for (int h = 0; h < 2; h++) {                                   \
            f2 s0 = azv[h] * (q0).z + (q0).w;                           \
            s0    = ayv[h] * (q0).y + s0;                               \
            s0    = axv[h] * (q0).x + s0;                               \
            f2 s1 = azv[h] * (q1).z + (q1).w;                           \
            s1    = ayv[h] * (q1).y + s1;                               \
            s1    = axv[h] * (q1).x + s1;                               \
            mnv[h][0] = fminf(fminf(mnv[h][0], s0[0]), s1[0]);          \
            mnv[h][1] = fminf(fminf(mnv[h][1], s0[1]), s1[1]);          \
        }                                                               \
    } while (0)

// ---- tiny preprocessing: pack (-2x,-2y,-2z,|p|^2) per point, zero outputs ----
__global__ void prep_pts(const float* __restrict__ pos,
                         const float* __restrict__ xhat,
                         float4* __restrict__ prep, int totalP, int totalX,
                         float* __restrict__ out) {
    const int t = blockIdx.x * blockDim.x + threadIdx.x;
    if (t == 0) { out[0] = 0.0f; out[1] = 0.0f; }
    const int total  = totalP + totalX;
    const int stride = gridDim.x * blockDim.x;
    for (int i = t; i < total; i += stride) {
        const float* src = (i < totalP) ? (pos + (size_t)i * 3)
                                        : (xhat + (size_t)(i - totalP) * 3);
        float x = src[0], y = src[1], z = src[2];
        prep[i] = make_float4(-2.0f * x, -2.0f * y, -2.0f * z,
                              x * x + y * y + z * z);
    }
}

// ---- main: db points via wave-uniform loads (SGPR broadcast), no LDS ----
__global__ __launch_bounds__(TPB, 4) void nn_min(
        const float* __restrict__ pos, const float* __restrict__ xhat,
        const float4* __restrict__ prep,
        float* __restrict__ part, int N, int M, int mx) {
    const int bz  = blockIdx.z;
    const int b   = bz >> 1;
    const int dir = bz & 1;
    // dir 0: queries = pos (N), database = xhat (M) -> dist1
    // dir 1: queries = xhat (M), database = pos (N) -> dist2
    const float* A  = dir ? xhat : pos;
    const int NA = dir ? M : N;
    const int NB = dir ? N : M;
    const int G  = gridDim.y;
    float* outp = part + (size_t)(bz * G + blockIdx.y) * mx;

    // database section in prep: pos at [0, 2N), xhat at [2N, 2N+2M)
    const float4* __restrict__ Bq =
        dir ? (prep + (size_t)b * NB)                       // db = pos
            : (prep + (size_t)(2 * N) + (size_t)b * NB);    // db = xhat
    const int mbase = blockIdx.y * CHUNK;
    const int mlen  = min(CHUNK, NB - mbase);               // 512 here
    const float4* __restrict__ q = Bq + mbase;              // uniform base

    // ---- load query points into register float2 pairs ----
    const int i0 = blockIdx.x * (TPB * PTS) + threadIdx.x;
    f2 axv[2], ayv[2], azv[2], cav[2], mnv[2];
#pragma unroll
    for (int h = 0; h < 2; h++) {
#pragma unroll
        for (int u = 0; u < 2; u++) {
            int i  = i0 + (h * 2 + u) * TPB;
            int ic = i < NA ? i : NA - 1;        // clamp (no OOB read)
            const float* p = A + (size_t)(b * NA + ic) * 3;
            float x = p[0], y = p[1], z = p[2];
            axv[h][u] = x; ayv[h][u] = y; azv[h][u] = z;
            cav[h][u] = x * x + y * y + z * z;
            mnv[h][u] = 3.4e38f;
        }
    }

    // ---- core: 4 db points per iter, depth-1 scalar prefetch ----
    int j = 0;
    if (mlen >= 8) {
        float4 c0 = q[0], c1 = q[1], c2 = q[2], c3 = q[3];
        for (; j + 8 <= mlen; j += 4) {
            float4 n0 = q[j + 4], n1 = q[j + 5];  // next group: s_loads issue
            float4 n2 = q[j + 6], n3 = q[j + 7];  // before current compute
            PAIR_COMPUTE(c0, c1);
            PAIR_COMPUTE(c2, c3);
            c0 = n0; c1 = n1; c2 = n2; c3 = n3;
        }
        PAIR_COMPUTE(c0, c1);                     // drain last group
        PAIR_COMPUTE(c2, c3);
        j += 4;
    }
    for (; j + 2 <= mlen; j += 2) {
        float4 q0 = q[j], q1 = q[j + 1];
        PAIR_COMPUTE(q0, q1);
    }
    for (; j < mlen; ++j) {                      // odd tail (not hit at 512)
        float4 qs = q[j];
#pragma unroll
        for (int h = 0; h < 2; h++) {
            f2 s = azv[h] * qs.z + qs.w;
            s    = ayv[h] * qs.y + s;
            s    = axv[h] * qs.x + s;
            mnv[h][0] = fminf(mnv[h][0], s[0]);
            mnv[h][1] = fminf(mnv[h][1], s[1]);
        }
    }

    // ---- store partial min per (query, group): plain coalesced store ----
#pragma unroll
    for (int h = 0; h < 2; h++)
#pragma unroll
        for (int u = 0; u < 2; u++) {
            int i = i0 + (h * 2 + u) * TPB;
            if (i < NA)
                outp[i] = fmaxf(cav[h][u] + mnv[h][u], 0.0f);
        }
}

__global__ void reduce_loss(const float* __restrict__ part,
                            int N, int M, int mx, int G, int nbz,
                            float inv1, float inv2, float* __restrict__ out) {
    const int total  = nbz * mx;
    const int stride = gridDim.x * blockDim.x;
    float s = 0.0f;
    for (int t = blockIdx.x * blockDim.x + threadIdx.x; t < total; t += stride) {
        int bz = t / mx;
        int i  = t - bz * mx;
        int dir = bz & 1;
        int NA  = dir ? M : N;
        if (i < NA) {
            const float* p = part + (size_t)(bz * G) * mx + i;
            float mn = p[0];
            for (int g = 1; g < G; ++g)          // coalesced across i per g
                mn = fminf(mn, p[(size_t)g * mx]);
            s += mn * (dir ? inv2 : inv1);
        }
    }
    __shared__ float sh[TPB];
    sh[threadIdx.x] = s;
    __syncthreads();
    for (int off = TPB / 2; off > 0; off >>= 1) {
        if (threadIdx.x < off) sh[threadIdx.x] += sh[threadIdx.x + off];
        __syncthreads();
    }
    if (threadIdx.x == 0) {
        atomicAdd(&out[0], sh[0]);   // loss
        atomicAdd(&out[1], sh[0]);   // rec_loss (identical)
    }
}

extern "C" void kernel_launch(void* const* d_in, const int* in_sizes, int n_in,
                              void* d_out, int out_size, void* d_ws, size_t ws_size,
                              hipStream_t stream) {
    const float* pos  = (const float*)d_in[0];
    const float* xhat = (const float*)d_in[1];
    const int B = 2;
    const int N = in_sizes[0] / (B * 3);   // 8192
    const int M = in_sizes[1] / (B * 3);   // 8192
    float* out  = (float*)d_out;
    float* part = (float*)d_ws;

    const int mx    = N > M ? N : M;
    const int tiles = (mx + TPB * PTS - 1) / (TPB * PTS);  // 8
    const int G     = (mx + CHUNK - 1) / CHUNK;            // 16

    // prep array lives after the partials in ws
    const size_t part_floats = (size_t)(B * 2) * G * mx;   // 2 MB / 4
    float4* prep = (float4*)(part + part_floats);
    const int totalP = B * N, totalX = B * M;

    prep_pts<<<(totalP + totalX + TPB - 1) / TPB, TPB, 0, stream>>>(
        pos, xhat, prep, totalP, totalX, out);

    dim3 grid(tiles, G, B * 2);                            // 512 blocks
    nn_min<<<grid, TPB, 0, stream>>>(pos, xhat, prep, part, N, M, mx);

    reduce_loss<<<128, TPB, 0, stream>>>(part, N, M, mx, G, B * 2,
                                         1.0f / (B * N), 1.0f / (B * M), out);
}

// Round 4
// 90.279 us; speedup vs baseline: 1.2997x; 1.2997x over previous
//
#include <hip/hip_runtime.h>

#define TPB 256
#define QW  16   // queries per wave (held as wave-uniform register values)

typedef float f2 __attribute__((ext_vector_type(2)));

// ws float4 layout:
//   qPos(b) at [b*N)            : (x,y,z,|a|^2) quads for pos
//   qXh(b)  at [B*N + b*M)      : quads for xhat
//   dPos(b) at [B*N+B*M + b*2*NPp) : pair-interleaved db of pos:
//          pair j -> (-2x0,-2x1,-2y0,-2y1), (-2z0,-2z1, n0, n1)
//   dXh(b)  at [.. + B*2*NPp + b*2*NPx)

__global__ void prep_pts(const float* __restrict__ pos,
                         const float* __restrict__ xhat,
                         float4* __restrict__ ws4,
                         int N, int M, int B,
                         float* __restrict__ out) {
    const int NPp = (N + 1) >> 1, NPx = (M + 1) >> 1;
    const int qXhBase  = B * N;
    const int dPosBase = B * N + B * M;
    const int dXhBase  = dPosBase + B * 2 * NPp;
    const int totP = B * NPp, totX = B * NPx;
    const int tid = blockIdx.x * blockDim.x + threadIdx.x;
    if (tid == 0) { out[0] = 0.0f; out[1] = 0.0f; }
    const int stride = gridDim.x * blockDim.x;
    for (int t = tid; t < totP + totX; t += stride) {
        const float* src; int b, j, NB, qBase, dBase;
        if (t < totP) {
            b = t / NPp; j = t - b * NPp; src = pos;  NB = N;
            qBase = b * N;            dBase = dPosBase + b * 2 * NPp;
        } else {
            int u = t - totP;
            b = u / NPx; j = u - b * NPx; src = xhat; NB = M;
            qBase = qXhBase + b * M;  dBase = dXhBase + b * 2 * NPx;
        }
        const int i0 = 2 * j;
        const int i1 = min(2 * j + 1, NB - 1);
        const float* p0 = src + (size_t)(b * NB + i0) * 3;
        const float* p1 = src + (size_t)(b * NB + i1) * 3;
        float x0 = p0[0], y0 = p0[1], z0 = p0[2];
        float x1 = p1[0], y1 = p1[1], z1 = p1[2];
        float n0 = x0 * x0 + y0 * y0 + z0 * z0;
        float n1 = x1 * x1 + y1 * y1 + z1 * z1;
        ws4[qBase + i0] = make_float4(x0, y0, z0, n0);
        if (i1 != i0) ws4[qBase + i1] = make_float4(x1, y1, z1, n1);
        ws4[dBase + 2 * j]     = make_float4(-2.0f * x0, -2.0f * x1,
                                             -2.0f * y0, -2.0f * y1);
        ws4[dBase + 2 * j + 1] = make_float4(-2.0f * z0, -2.0f * z1, n0, n1);
    }
}

// db pair (dA,dB) vs QW uniform queries; fma chain + min3 fold identical
// ordering to the verified kernels (dist bits unchanged).
#define COMPUTE(dA, dB)                                                 \
    do {                                                                \
        f2 xx = {(dA).x, (dA).y};                                       \
        f2 yy = {(dA).z, (dA).w};                                       \
        f2 zz = {(dB).x, (dB).y};                                       \
        f2 ww = {(dB).z, (dB).w};                                       \
        _Pragma("unroll")                                               \
        for (int k = 0; k < QW; k++) {                                  \
            f2 sv = zz * qz[k] + ww;                                    \
            sv    = yy * qy[k] + sv;                                    \
            sv    = xx * qx[k] + sv;                                    \
            vmn[k] = fminf(fminf(vmn[k], sv[0]), sv[1]);  /* v_min3 */  \
        }                                                               \
    } while (0)

#define LDPAIR(d0, d1, t_)                                              \
    do {                                                                \
        int p_ = (t_) * 64 + lane;                                      \
        p_ = p_ < NP ? p_ : NP - 1;          /* dup pair: min-safe */   \
        d0 = dp[2 * p_];                                                \
        d1 = dp[2 * p_ + 1];                                            \
    } while (0)

__global__ __launch_bounds__(TPB, 2) void nn_loss(
        const float4* __restrict__ ws4,
        int N, int M, int B, int wps,
        float inv1, float inv2, float* __restrict__ out) {
    const int NPp = (N + 1) >> 1, NPx = (M + 1) >> 1;
    const int qXhBase  = B * N;
    const int dPosBase = B * N + B * M;
    const int dXhBase  = dPosBase + B * 2 * NPp;

    const int wv   = threadIdx.x >> 6;
    const int lane = threadIdx.x & 63;
    const int gw   = blockIdx.x * (TPB / 64) + wv;
    const int s    = gw / wps;           // stream: b*2 + dir
    const int w    = gw - s * wps;       // wave within stream
    float acc = 0.0f;

    if (s < B * 2) {
        const int dir = s & 1, b = s >> 1;
        const int NA  = dir ? M : N;               // #queries
        const int NP  = dir ? NPp : NPx;           // db pairs (db = dir? pos : xhat)
        const float4* __restrict__ qp =
            ws4 + (dir ? qXhBase + b * M : b * N);
        const float4* __restrict__ dp =
            ws4 + (dir ? dPosBase + b * 2 * NPp : dXhBase + b * 2 * NPx);
        const float invW = dir ? inv2 : inv1;

        // wave-uniform query registers (all lanes load identical values)
        float qx[QW], qy[QW], qz[QW];
#pragma unroll
        for (int k = 0; k < QW; k++) {
            int iq = w * QW + k;
            int ic = iq < NA ? iq : NA - 1;        // clamp; masked at sum
            float4 v = qp[ic];
            qx[k] = v.x; qy[k] = v.y; qz[k] = v.z;
        }
        float vmn[QW];
#pragma unroll
        for (int k = 0; k < QW; k++) vmn[k] = 3.4e38f;

        const int T = (NP + 63) >> 6;              // pair-iters per lane (64)
        float4 A0, A1, B0, B1;
        LDPAIR(A0, A1, 0);
        int t = 0;
        if (T >= 2) {
            LDPAIR(B0, B1, 1);
            for (; t + 3 < T; t += 2) {            // depth-2 pipeline
                float4 C0, C1, D0, D1;
                LDPAIR(C0, C1, t + 2);
                COMPUTE(A0, A1);
                LDPAIR(D0, D1, t + 3);
                COMPUTE(B0, B1);
                A0 = C0; A1 = C1; B0 = D0; B1 = D1;
            }
            COMPUTE(A0, A1);
            COMPUTE(B0, B1);
            t += 2;
            if (t < T) { LDPAIR(A0, A1, t); COMPUTE(A0, A1); }
        } else {
            COMPUTE(A0, A1);
        }

        // 64-lane min butterfly per query, then weighted sum (uniform result)
#pragma unroll
        for (int k = 0; k < QW; k++) {
            float m = vmn[k];
            m = fminf(m, __shfl_xor(m, 1));
            m = fminf(m, __shfl_xor(m, 2));
            m = fminf(m, __shfl_xor(m, 4));
            m = fminf(m, __shfl_xor(m, 8));
            m = fminf(m, __shfl_xor(m, 16));
            m = fminf(m, __shfl_xor(m, 32));
            int iq = w * QW + k;
            if (iq < NA) {
                float qn = qp[iq].w;               // |a|^2
                acc += fmaxf(qn + m, 0.0f) * invW;
            }
        }
    }

    // block reduce: one atomic per block
    __shared__ float ssum[TPB / 64];
    if (lane == 0) ssum[wv] = acc;
    __syncthreads();
    if (threadIdx.x == 0) {
        float tot = 0.0f;
#pragma unroll
        for (int i = 0; i < TPB / 64; i++) tot += ssum[i];
        atomicAdd(&out[0], tot);   // loss
        atomicAdd(&out[1], tot);   // rec_loss (identical)
    }
}

extern "C" void kernel_launch(void* const* d_in, const int* in_sizes, int n_in,
                              void* d_out, int out_size, void* d_ws, size_t ws_size,
                              hipStream_t stream) {
    const float* pos  = (const float*)d_in[0];
    const float* xhat = (const float*)d_in[1];
    const int B = 2;
    const int N = in_sizes[0] / (B * 3);   // 8192
    const int M = in_sizes[1] / (B * 3);   // 8192
    float* out   = (float*)d_out;
    float4* ws4  = (float4*)d_ws;

    const int NPp = (N + 1) / 2, NPx = (M + 1) / 2;
    const int totPairs = B * NPp + B * NPx;                // 16384
    prep_pts<<<(totPairs + TPB - 1) / TPB, TPB, 0, stream>>>(
        pos, xhat, ws4, N, M, B, out);

    const int mxq = N > M ? N : M;
    const int wps = (mxq + QW - 1) / QW;                   // 512 waves/stream
    const int totalWaves = B * 2 * wps;                    // 2048
    const int blocks = (totalWaves + (TPB / 64) - 1) / (TPB / 64);  // 512
    nn_loss<<<blocks, TPB, 0, stream>>>(ws4, N, M, B, wps,
                                        1.0f / (B * N), 1.0f / (B * M), out);
}